// Round 8
// baseline (528.517 us; speedup 1.0000x reference)
//
#include <hip/hip_runtime.h>
#include <math.h>

#define BB 16
#define NN 128
#define HH 256
#define EE (NN*(NN-1))   // 16256

typedef unsigned short ushort_t;
typedef __attribute__((ext_vector_type(8))) short bf16x8;
typedef __attribute__((ext_vector_type(4))) float f32x4;

__device__ __forceinline__ ushort_t f2b(float f) {
  unsigned u = __builtin_bit_cast(unsigned, f);
  unsigned r = (u + 0x7fffu + ((u >> 16) & 1u)) >> 16;
  return (ushort_t)r;
}

// fast tanh: (e-1)/(e+1), e = 2^(2x*log2e); clamped, ~6 VALU ops
__device__ __forceinline__ float fast_tanh(float x) {
  float xx = fminf(fmaxf(x, -15.f), 15.f);
  float e = __builtin_amdgcn_exp2f(xx * 2.8853900817779268f);
  return (e - 1.f) * __builtin_amdgcn_rcpf(e + 1.f);
}
__device__ __forceinline__ float fast_sigmoid(float x) {
  float xx = fminf(fmaxf(x, -30.f), 30.f);
  float e = __builtin_amdgcn_exp2f(-xx * 1.4426950408889634f);
  return __builtin_amdgcn_rcpf(1.f + e);
}

// ---------------------------------------------------------------------------
// K1: per-node geometry + rel_feat (15)
// ---------------------------------------------------------------------------
__global__ void k_node_geom(const float* __restrict__ inputs,
                            const float* __restrict__ pfield,
                            float* __restrict__ geom, float* __restrict__ relf) {
  int idx = blockIdx.x * blockDim.x + threadIdx.x;
  if (idx >= BB * NN) return;
  float px = inputs[idx*4+0], py = inputs[idx*4+1];
  float vx = inputs[idx*4+2], vy = inputs[idx*4+3];
  float fx = pfield[idx*2+0], fy = pfield[idx*2+1];
  float th = atan2f(vy, vx);
  float c = cosf(th), s = sinf(th);
  float lpx =  c*px + s*py, lpy = -s*px + c*py;
  float lvx =  c*vx + s*vy, lvy = -s*vx + c*vy;
  float lfx =  c*fx + s*fy, lfy = -s*fx + c*fy;
  float np_ = sqrtf(px*px + py*py + 1e-8f);
  float nv_ = sqrtf(vx*vx + vy*vy + 1e-8f);
  float ang  = atan2f(lpy, lpx);
  float vang = atan2f(lvy, lvx);
  float* g = geom + idx*16;
  g[0]=px; g[1]=py; g[2]=vx; g[3]=vy; g[4]=th; g[5]=c; g[6]=s;
  g[7]=lpx; g[8]=lpy; g[9]=lvx; g[10]=lvy; g[11]=lfx; g[12]=lfy;
  float* r = relf + idx*16;
  r[0]=lpx; r[1]=lpy; r[2]=lvx; r[3]=lvy; r[4]=np_; r[5]=ang; r[6]=nv_; r[7]=vang; r[8]=th;
  r[9]=lpx; r[10]=lpy; r[11]=lvx; r[12]=lvy; r[13]=lfx; r[14]=lfy;
}

// ---------------------------------------------------------------------------
// Kcvt: msg_fc2_w[1], pm_fc2_w[1] -> bf16; pm_fc1_w[1] -> bf16 [256][32] K-pad
// ---------------------------------------------------------------------------
__global__ void k_cvt(const float* __restrict__ w2, const float* __restrict__ pw2,
                      const float* __restrict__ pw1,
                      ushort_t* __restrict__ w2b, ushort_t* __restrict__ pw2b,
                      ushort_t* __restrict__ pw1b) {
  int idx = blockIdx.x * 256 + threadIdx.x;
  if (idx < HH*HH) {
    w2b[idx] = f2b(w2[HH*HH + idx]);
  } else if (idx < 2*HH*HH) {
    int k = idx - HH*HH;
    pw2b[k] = f2b(pw2[HH*HH + k]);
  } else if (idx < 2*HH*HH + HH*32) {
    int k = idx - 2*HH*HH;          // 0..8191
    int col = k >> 5, kk = k & 31;
    pw1b[k] = (kk < 24) ? f2b(pw1[col*24 + kk]) : (ushort_t)0;
  }
}

// ---------------------------------------------------------------------------
// K2: Ha = hidden@W1a.T + b1, Hb = hidden@W1b.T
// grid 512: block = (node n, batch-quarter), 4 rows each -> 2 blocks/CU
// ---------------------------------------------------------------------------
__global__ __launch_bounds__(256) void k_hab(const float* __restrict__ hidden,
                                             const float* __restrict__ w1,
                                             const float* __restrict__ b1,
                                             float* __restrict__ Ha,
                                             float* __restrict__ Hb) {
  int n = blockIdx.x >> 2, qtr = blockIdx.x & 3;
  int tid = threadIdx.x;
  __shared__ float x[4][HH];
  for (int q = 0; q < 4; ++q) {
    int b = qtr*4 + q;
    x[q][tid] = hidden[(b*NN + n)*HH + tid];
  }
  __syncthreads();
  const float* wa = w1 + (HH*2*HH) + tid*(2*HH);
  const float* wb = wa + HH;
  float accA[4], accB[4];
  float bias = b1[HH + tid];
  #pragma unroll
  for (int q = 0; q < 4; ++q) { accA[q] = bias; accB[q] = 0.f; }
  for (int k = 0; k < HH; k += 4) {
    float4 a4 = *(const float4*)(wa + k);
    float4 b4 = *(const float4*)(wb + k);
    #pragma unroll
    for (int q = 0; q < 4; ++q) {
      float4 x4 = *(const float4*)(&x[q][k]);
      accA[q] += x4.x*a4.x + x4.y*a4.y + x4.z*a4.z + x4.w*a4.w;
      accB[q] += x4.x*b4.x + x4.y*b4.y + x4.z*b4.z + x4.w*b4.w;
    }
  }
  for (int q = 0; q < 4; ++q) {
    int b = qtr*4 + q;
    Ha[(b*NN + n)*HH + tid] = accA[q];
    Hb[(b*NN + n)*HH + tid] = accB[q];
  }
}

// ---------------------------------------------------------------------------
// K3: per (b, recv j, half): 64 senders per block.
// m1s bf16 [64][256], XOR-swizzle byte ^= (row&15)<<4.
// p1 (present fc1) now via MFMA: attrB bf16 [64][32] (K=24 padded), swizzle
// byte ^= ((row&3)<<4). grid 4096, 4 waves, 4 blocks/CU.
// ---------------------------------------------------------------------------
__global__ __launch_bounds__(256, 4) void k_edge(
    const float* __restrict__ Ha, const float* __restrict__ Hb,
    const float* __restrict__ geom, const float* __restrict__ edges,
    const ushort_t* __restrict__ w2b, const float* __restrict__ b2,
    const ushort_t* __restrict__ pw2b, const float* __restrict__ pb2,
    const ushort_t* __restrict__ pw1b, const float* __restrict__ pb1,
    float* __restrict__ agg0, float* __restrict__ agg1,
    float* __restrict__ pagg0, float* __restrict__ pagg1) {
  int half = blockIdx.x & 1;
  int j = (blockIdx.x >> 1) & 127;
  int b = blockIdx.x >> 8;
  int tid = threadIdx.x;
  int lane = tid & 63;
  int wv = tid >> 6;
  int lrow = lane & 15, lk = lane >> 4;

  __shared__ __align__(16) unsigned char m1s[64*512];   // 32 KB bf16 [64][256]
  __shared__ __align__(16) unsigned char attrB[64*64];  // 4 KB bf16 [64][32]
  __shared__ float HajS[HH];
  __shared__ float wgtS[64];
  __shared__ float gjS[13];

  HajS[tid] = Ha[(b*NN + j)*HH + tid];
  if (tid < 13) gjS[tid] = geom[(b*NN + j)*16 + tid];
  __syncthreads();

  // ---- phase A: edge attrs (bf16, swizzled) + weights (threads 0..63) ----
  if (tid < 64) {
    int il = tid;
    int i = half*64 + il;
    const float* gi = geom + (b*NN + i)*16;
    float dpx = gi[0]-gjS[0], dpy = gi[1]-gjS[1];
    float dvx = gi[2]-gjS[2], dvy = gi[3]-gjS[3];
    float dth = gi[4]-gjS[4];
    float cj = gjS[5], sj = gjS[6];
    float ci = gi[5],  si = gi[6];
    float ndp = sqrtf(dpx*dpx + dpy*dpy + 1e-8f);
    float ndv = sqrtf(dvx*dvx + dvy*dvy + 1e-8f);
    float r1x =  cj*dpx + sj*dpy, r1y = -sj*dpx + cj*dpy;
    float v1x =  cj*dvx + sj*dvy, v1y = -sj*dvx + cj*dvy;
    float r2x = -(ci*dpx + si*dpy), r2y = si*dpx - ci*dpy;
    float v2x = -(ci*dvx + si*dvy), v2y = si*dvx - ci*dvy;
    float f[24];
    f[0]=r1x; f[1]=r1y; f[2]=v1x; f[3]=v1y;
    f[4]=ndp; f[5]=atan2f(r1y, r1x);
    f[6]=ndv; f[7]=atan2f(v1y, v1x); f[8]=dth;
    f[9]=r2x; f[10]=r2y; f[11]=v2x; f[12]=v2y;
    f[13]=ndp; f[14]=atan2f(r2y, r2x);
    f[15]=ndv; f[16]=atan2f(v2y, v2x); f[17]=-dth;
    f[18]=gjS[7]; f[19]=gjS[8]; f[20]=gjS[9];
    f[21]=gjS[10]; f[22]=gjS[11]; f[23]=gjS[12];
    #pragma unroll
    for (int kb = 0; kb < 4; ++kb) {
      bf16x8 v;
      #pragma unroll
      for (int e = 0; e < 8; ++e) {
        int k = kb*8 + e;
        v[e] = (k < 24) ? (short)f2b(f[k]) : (short)0;
      }
      *reinterpret_cast<bf16x8*>(attrB + il*64 + ((kb*16) ^ ((il&3)<<4))) = v;
    }
    float w = 0.f;
    if (i != j) {
      int e = i*127 + (j < i ? j : j-1);
      w = edges[(b*EE + e)*2 + 1];
    }
    wgtS[il] = w;
  }

  // ---- phase B1: m1[row][h] = tanh(Ha[j][h] + Hb[i][h]) -> bf16 LDS ----
  {
    float haj = HajS[tid];
    const float* hb = Hb + (b*NN + half*64)*HH + tid;
    #pragma unroll
    for (int i0 = 0; i0 < 64; i0 += 8) {
      float v[8];
      #pragma unroll
      for (int u = 0; u < 8; ++u) v[u] = hb[(i0+u)*HH];
      #pragma unroll
      for (int u = 0; u < 8; ++u) {
        int row = i0 + u;
        *(ushort_t*)(m1s + row*512 + ((tid*2) ^ ((row&15)<<4))) =
            f2b(fast_tanh(haj + v[u]));
      }
    }
  }
  __syncthreads();

  f32x4 zero = {0.f, 0.f, 0.f, 0.f};

  // ---- GEMM1: m2 = tanh(m1 @ W2.T + b2); weighted col-sum -> agg partial ---
  {
    f32x4 acc[4][4];
    #pragma unroll
    for (int rt = 0; rt < 4; ++rt)
      #pragma unroll
      for (int nt = 0; nt < 4; ++nt) acc[rt][nt] = zero;
    for (int kk = 0; kk < 8; ++kk) {
      bf16x8 afr[4];
      #pragma unroll
      for (int rt = 0; rt < 4; ++rt) {
        int row = rt*16 + lrow;
        afr[rt] = *reinterpret_cast<const bf16x8*>(
            m1s + row*512 + ((kk*64 + lk*16) ^ ((row&15)<<4)));
      }
      #pragma unroll
      for (int nt = 0; nt < 4; ++nt) {
        int col = wv*64 + nt*16 + lrow;
        bf16x8 bfr = *reinterpret_cast<const bf16x8*>(w2b + col*HH + kk*32 + lk*8);
        #pragma unroll
        for (int rt = 0; rt < 4; ++rt)
          acc[rt][nt] = __builtin_amdgcn_mfma_f32_16x16x32_bf16(afr[rt], bfr, acc[rt][nt], 0, 0, 0);
      }
    }
    float* aggOut = half ? agg1 : agg0;
    #pragma unroll
    for (int nt = 0; nt < 4; ++nt) {
      int col = wv*64 + nt*16 + lrow;
      float bias = b2[col];
      float p = 0.f;
      #pragma unroll
      for (int rt = 0; rt < 4; ++rt)
        #pragma unroll
        for (int r = 0; r < 4; ++r) {
          int row = rt*16 + lk*4 + r;
          p += fast_tanh(acc[rt][nt][r] + bias) * wgtS[row];
        }
      p += __shfl_xor(p, 16);
      p += __shfl_xor(p, 32);
      if (lane < 16)
        aggOut[(b*NN + j)*HH + wv*64 + nt*16 + lane] = p * (1.0f/127.0f);
    }
  }
  __syncthreads();

  // ---- phase B2 (MFMA): p1 = relu(attr @ pw1.T + pb1) -> bf16 m1s ---------
  // M=64, N=256 (64/wave), K=32 (24 padded): 16 MFMA per wave, one K-step.
  {
    f32x4 acc[4][4];
    #pragma unroll
    for (int rt = 0; rt < 4; ++rt)
      #pragma unroll
      for (int nt = 0; nt < 4; ++nt) acc[rt][nt] = zero;
    bf16x8 afr[4];
    #pragma unroll
    for (int rt = 0; rt < 4; ++rt) {
      int row = rt*16 + lrow;
      afr[rt] = *reinterpret_cast<const bf16x8*>(
          attrB + row*64 + ((lk*16) ^ ((lrow&3)<<4)));
    }
    #pragma unroll
    for (int nt = 0; nt < 4; ++nt) {
      int col = wv*64 + nt*16 + lrow;
      bf16x8 bfr = *reinterpret_cast<const bf16x8*>(pw1b + col*32 + lk*8);
      #pragma unroll
      for (int rt = 0; rt < 4; ++rt)
        acc[rt][nt] = __builtin_amdgcn_mfma_f32_16x16x32_bf16(afr[rt], bfr, acc[rt][nt], 0, 0, 0);
    }
    #pragma unroll
    for (int nt = 0; nt < 4; ++nt) {
      int col = wv*64 + nt*16 + lrow;
      float bias = pb1[col];
      #pragma unroll
      for (int rt = 0; rt < 4; ++rt)
        #pragma unroll
        for (int r = 0; r < 4; ++r) {
          int row = rt*16 + lk*4 + r;
          *(ushort_t*)(m1s + row*512 + ((col*2) ^ ((row&15)<<4))) =
              f2b(fmaxf(acc[rt][nt][r] + bias, 0.f));
        }
    }
  }
  __syncthreads();

  // ---- GEMM2: p2 = relu(p1 @ pW2.T + pb2); weighted col-sum -> pagg -------
  {
    f32x4 acc[4][4];
    #pragma unroll
    for (int rt = 0; rt < 4; ++rt)
      #pragma unroll
      for (int nt = 0; nt < 4; ++nt) acc[rt][nt] = zero;
    for (int kk = 0; kk < 8; ++kk) {
      bf16x8 afr[4];
      #pragma unroll
      for (int rt = 0; rt < 4; ++rt) {
        int row = rt*16 + lrow;
        afr[rt] = *reinterpret_cast<const bf16x8*>(
            m1s + row*512 + ((kk*64 + lk*16) ^ ((row&15)<<4)));
      }
      #pragma unroll
      for (int nt = 0; nt < 4; ++nt) {
        int col = wv*64 + nt*16 + lrow;
        bf16x8 bfr = *reinterpret_cast<const bf16x8*>(pw2b + col*HH + kk*32 + lk*8);
        #pragma unroll
        for (int rt = 0; rt < 4; ++rt)
          acc[rt][nt] = __builtin_amdgcn_mfma_f32_16x16x32_bf16(afr[rt], bfr, acc[rt][nt], 0, 0, 0);
      }
    }
    float* paggOut = half ? pagg1 : pagg0;
    #pragma unroll
    for (int nt = 0; nt < 4; ++nt) {
      int col = wv*64 + nt*16 + lrow;
      float bias = pb2[col];
      float p = 0.f;
      #pragma unroll
      for (int rt = 0; rt < 4; ++rt)
        #pragma unroll
        for (int r = 0; r < 4; ++r) {
          int row = rt*16 + lk*4 + r;
          p += fmaxf(acc[rt][nt][r] + bias, 0.f) * wgtS[row];
        }
      p += __shfl_xor(p, 16);
      p += __shfl_xor(p, 32);
      if (lane < 16)
        paggOut[(b*NN + j)*HH + wv*64 + nt*16 + lane] = p * (1.0f/127.0f);
    }
  }
}

// ---------------------------------------------------------------------------
// K4: GRU gates + output MLP + global-frame outputs.
// grid 512: block = (node n, batch-quarter), 4 rows -> 2 blocks/CU.
// ---------------------------------------------------------------------------
__global__ __launch_bounds__(256) void k_gru(
    const float* __restrict__ inputs, const float* __restrict__ hidden,
    const float* __restrict__ geom, const float* __restrict__ relf,
    const float* __restrict__ agg0, const float* __restrict__ agg1,
    const float* __restrict__ pagg0, const float* __restrict__ pagg1,
    const float* __restrict__ hr_w, const float* __restrict__ hi_w, const float* __restrict__ hh_w,
    const float* __restrict__ pr_w, const float* __restrict__ pr_b,
    const float* __restrict__ pi_w, const float* __restrict__ pi_b,
    const float* __restrict__ pn_w, const float* __restrict__ pn_b,
    const float* __restrict__ ir_w, const float* __restrict__ ir_b,
    const float* __restrict__ ii_w, const float* __restrict__ ii_b,
    const float* __restrict__ in_w, const float* __restrict__ in_b,
    const float* __restrict__ ow1, const float* __restrict__ ob1,
    const float* __restrict__ ow2, const float* __restrict__ ob2,
    const float* __restrict__ ow3, const float* __restrict__ ob3,
    float* __restrict__ out_o, float* __restrict__ out_h) {
  int n = blockIdx.x >> 2, qtr = blockIdx.x & 3;
  int tid = threadIdx.x;
  __shared__ float paS[4][HH], agS[4][HH], hS[4][HH], t0S[4][HH], t1S[4][HH];
  __shared__ float relS[4][16];
  __shared__ float predS[4][4];

  for (int q = 0; q < 4; ++q) {
    int b = qtr*4 + q;
    int base = (b*NN + n)*HH;
    paS[q][tid] = pagg0[base + tid] + pagg1[base + tid];
    agS[q][tid] = agg0[base + tid] + agg1[base + tid];
    hS[q][tid]  = hidden[base + tid];
  }
  if (tid < 64) {
    int q = tid >> 4, k = tid & 15;
    int b = qtr*4 + q;
    relS[q][k] = (k < 15) ? relf[(b*NN + n)*16 + k] : 0.f;
  }
  __syncthreads();

  int h = tid;
  float aR[4], aI[4], aN[4], aH[4];
  float br = ir_b[h] + pr_b[h];
  float bi = ii_b[h] + pi_b[h];
  float bn = in_b[h] + pn_b[h];
  #pragma unroll
  for (int q = 0; q < 4; ++q) { aR[q]=br; aI[q]=bi; aN[q]=bn; aH[q]=0.f; }

  for (int k = 0; k < 15; ++k) {
    float wr = ir_w[h*15+k], wi = ii_w[h*15+k], wn = in_w[h*15+k];
    #pragma unroll
    for (int q = 0; q < 4; ++q) {
      float x = relS[q][k];
      aR[q] += x*wr; aI[q] += x*wi; aN[q] += x*wn;
    }
  }
  for (int k = 0; k < HH; k += 4) {
    float4 wpr = *(const float4*)(pr_w + h*HH + k);
    float4 wpi = *(const float4*)(pi_w + h*HH + k);
    float4 wpn = *(const float4*)(pn_w + h*HH + k);
    float4 whr = *(const float4*)(hr_w + h*HH + k);
    float4 whi = *(const float4*)(hi_w + h*HH + k);
    float4 whh = *(const float4*)(hh_w + h*HH + k);
    #pragma unroll
    for (int q = 0; q < 4; ++q) {
      float4 xp = *(const float4*)(&paS[q][k]);
      float4 xa = *(const float4*)(&agS[q][k]);
      aR[q] += xp.x*wpr.x + xp.y*wpr.y + xp.z*wpr.z + xp.w*wpr.w
             + xa.x*whr.x + xa.y*whr.y + xa.z*whr.z + xa.w*whr.w;
      aI[q] += xp.x*wpi.x + xp.y*wpi.y + xp.z*wpi.z + xp.w*wpi.w
             + xa.x*whi.x + xa.y*whi.y + xa.z*whi.z + xa.w*whi.w;
      aN[q] += xp.x*wpn.x + xp.y*wpn.y + xp.z*wpn.z + xp.w*wpn.w;
      aH[q] += xa.x*whh.x + xa.y*whh.y + xa.z*whh.z + xa.w*whh.w;
    }
  }
  #pragma unroll
  for (int q = 0; q < 4; ++q) {
    int b = qtr*4 + q;
    float r  = fast_sigmoid(aR[q]);
    float ig = fast_sigmoid(aI[q]);
    float ng = fast_tanh(aN[q] + r*aH[q]);
    float hn = (1.f - ig)*ng + ig*hS[q][h];
    out_h[(b*NN + n)*HH + h] = hn;
    t0S[q][h] = hn;
  }
  __syncthreads();

  {
    float a1[4];
    float bias = ob1[h];
    #pragma unroll
    for (int q = 0; q < 4; ++q) a1[q] = bias;
    for (int k = 0; k < HH; k += 4) {
      float4 w = *(const float4*)(ow1 + h*HH + k);
      #pragma unroll
      for (int q = 0; q < 4; ++q) {
        float4 x = *(const float4*)(&t0S[q][k]);
        a1[q] += x.x*w.x + x.y*w.y + x.z*w.z + x.w*w.w;
      }
    }
    __syncthreads();
    #pragma unroll
    for (int q = 0; q < 4; ++q) t1S[q][h] = fmaxf(a1[q], 0.f);
  }
  __syncthreads();

  {
    float a2[4];
    float bias = ob2[h];
    #pragma unroll
    for (int q = 0; q < 4; ++q) a2[q] = bias;
    for (int k = 0; k < HH; k += 4) {
      float4 w = *(const float4*)(ow2 + h*HH + k);
      #pragma unroll
      for (int q = 0; q < 4; ++q) {
        float4 x = *(const float4*)(&t1S[q][k]);
        a2[q] += x.x*w.x + x.y*w.y + x.z*w.z + x.w*w.w;
      }
    }
    __syncthreads();
    #pragma unroll
    for (int q = 0; q < 4; ++q) t0S[q][h] = fmaxf(a2[q], 0.f);
  }
  __syncthreads();

  if (tid < 16) {
    int o = tid >> 2, q = tid & 3;
    float acc = ob3[o];
    for (int k = 0; k < HH; ++k) acc += t0S[q][k]*ow3[o*HH + k];
    predS[q][o] = acc;
  }
  __syncthreads();
  if (tid < 4) {
    int q = tid;
    int b = qtr*4 + q;
    const float* g = geom + (b*NN + n)*16;
    float c = g[5], s = g[6];
    float p0 = predS[q][0], p1 = predS[q][1], p2 = predS[q][2], p3 = predS[q][3];
    int base = (b*NN + n)*4;
    out_o[base+0] = inputs[base+0] + (c*p0 - s*p1);
    out_o[base+1] = inputs[base+1] + (s*p0 + c*p1);
    out_o[base+2] = inputs[base+2] + (c*p2 - s*p3);
    out_o[base+3] = inputs[base+3] + (s*p2 + c*p3);
  }
}

// ---------------------------------------------------------------------------
extern "C" void kernel_launch(void* const* d_in, const int* in_sizes, int n_in,
                              void* d_out, int out_size, void* d_ws, size_t ws_size,
                              hipStream_t stream) {
  const float* inputs    = (const float*)d_in[0];
  const float* hidden    = (const float*)d_in[1];
  const float* edges     = (const float*)d_in[2];
  const float* pfield    = (const float*)d_in[3];
  const float* msg_fc1_w = (const float*)d_in[4];
  const float* msg_fc1_b = (const float*)d_in[5];
  const float* msg_fc2_w = (const float*)d_in[6];
  const float* msg_fc2_b = (const float*)d_in[7];
  const float* pm_fc1_w  = (const float*)d_in[8];
  const float* pm_fc1_b  = (const float*)d_in[9];
  const float* pm_fc2_w  = (const float*)d_in[10];
  const float* pm_fc2_b  = (const float*)d_in[11];
  const float* hr_w = (const float*)d_in[12];
  const float* hi_w = (const float*)d_in[13];
  const float* hh_w = (const float*)d_in[14];
  const float* pr_w = (const float*)d_in[15];
  const float* pr_b = (const float*)d_in[16];
  const float* pi_w = (const float*)d_in[17];
  const float* pi_b = (const float*)d_in[18];
  const float* pn_w = (const float*)d_in[19];
  const float* pn_b = (const float*)d_in[20];
  const float* ir_w = (const float*)d_in[21];
  const float* ir_b = (const float*)d_in[22];
  const float* ii_w = (const float*)d_in[23];
  const float* ii_b = (const float*)d_in[24];
  const float* in_w = (const float*)d_in[25];
  const float* in_b = (const float*)d_in[26];
  const float* ow1  = (const float*)d_in[27];
  const float* ob1  = (const float*)d_in[28];
  const float* ow2  = (const float*)d_in[29];
  const float* ob2  = (const float*)d_in[30];
  const float* ow3  = (const float*)d_in[31];
  const float* ob3  = (const float*)d_in[32];

  float* ws   = (float*)d_ws;
  float* geom = ws;                 // 32768
  float* relf = geom + 32768;       // 32768
  float* Ha   = relf + 32768;       // 524288
  float* Hb   = Ha   + 524288;      // 524288
  float* agg0 = Hb   + 524288;      // 524288
  float* agg1 = agg0 + 524288;      // 524288
  float* pagg0= agg1 + 524288;      // 524288
  float* pagg1= pagg0+ 524288;      // 524288
  ushort_t* w2b  = (ushort_t*)(pagg1 + 524288);  // 65536 bf16
  ushort_t* pw2b = w2b + HH*HH;                  // 65536 bf16
  ushort_t* pw1b = pw2b + HH*HH;                 // 8192 bf16 [256][32]

  float* out_o = (float*)d_out;           // (B,N,4)
  float* out_h = out_o + BB*NN*4;         // (B,N,H)

  k_node_geom<<<dim3(8), dim3(256), 0, stream>>>(inputs, pfield, geom, relf);
  k_cvt<<<dim3(544), dim3(256), 0, stream>>>(msg_fc2_w, pm_fc2_w,
      pm_fc1_w + HH*24, w2b, pw2b, pw1b);
  k_hab<<<dim3(512), dim3(256), 0, stream>>>(hidden, msg_fc1_w, msg_fc1_b, Ha, Hb);
  k_edge<<<dim3(BB*NN*2), dim3(256), 0, stream>>>(Ha, Hb, geom, edges,
      w2b, msg_fc2_b + HH, pw2b, pm_fc2_b + HH,
      pw1b, pm_fc1_b + HH, agg0, agg1, pagg0, pagg1);
  k_gru<<<dim3(512), dim3(256), 0, stream>>>(inputs, hidden, geom, relf,
      agg0, agg1, pagg0, pagg1,
      hr_w, hi_w, hh_w, pr_w, pr_b, pi_w, pi_b, pn_w, pn_b,
      ir_w, ir_b, ii_w, ii_b, in_w, in_b,
      ow1, ob1, ow2, ob2, ow3, ob3, out_o, out_h);
}

// Round 10
// 393.436 us; speedup vs baseline: 1.3433x; 1.3433x over previous
//
#include <hip/hip_runtime.h>
#include <math.h>

#define BB 16
#define NN 128
#define HH 256
#define EE (NN*(NN-1))   // 16256

typedef unsigned short ushort_t;
typedef unsigned int uint_t;
typedef __attribute__((ext_vector_type(8))) short bf16x8;
typedef __attribute__((ext_vector_type(4))) float f32x4;

__device__ __forceinline__ ushort_t f2b(float f) {
  unsigned u = __builtin_bit_cast(unsigned, f);
  unsigned r = (u + 0x7fffu + ((u >> 16) & 1u)) >> 16;
  return (ushort_t)r;
}
__device__ __forceinline__ float blo(uint_t u) {
  return __builtin_bit_cast(float, u << 16);
}
__device__ __forceinline__ float bhi(uint_t u) {
  return __builtin_bit_cast(float, u & 0xffff0000u);
}

// fast tanh: (e-1)/(e+1), e = 2^(2x*log2e); clamped
__device__ __forceinline__ float fast_tanh(float x) {
  float xx = fminf(fmaxf(x, -15.f), 15.f);
  float e = __builtin_amdgcn_exp2f(xx * 2.8853900817779268f);
  return (e - 1.f) * __builtin_amdgcn_rcpf(e + 1.f);
}
__device__ __forceinline__ float fast_sigmoid(float x) {
  float xx = fminf(fmaxf(x, -30.f), 30.f);
  float e = __builtin_amdgcn_exp2f(-xx * 1.4426950408889634f);
  return __builtin_amdgcn_rcpf(1.f + e);
}

// ---------------------------------------------------------------------------
// K1: per-node geometry + rel_feat (15)
// ---------------------------------------------------------------------------
__global__ void k_node_geom(const float* __restrict__ inputs,
                            const float* __restrict__ pfield,
                            float* __restrict__ geom, float* __restrict__ relf) {
  int idx = blockIdx.x * blockDim.x + threadIdx.x;
  if (idx >= BB * NN) return;
  float px = inputs[idx*4+0], py = inputs[idx*4+1];
  float vx = inputs[idx*4+2], vy = inputs[idx*4+3];
  float fx = pfield[idx*2+0], fy = pfield[idx*2+1];
  float th = atan2f(vy, vx);
  float c = cosf(th), s = sinf(th);
  float lpx =  c*px + s*py, lpy = -s*px + c*py;
  float lvx =  c*vx + s*vy, lvy = -s*vx + c*vy;
  float lfx =  c*fx + s*fy, lfy = -s*fx + c*fy;
  float np_ = sqrtf(px*px + py*py + 1e-8f);
  float nv_ = sqrtf(vx*vx + vy*vy + 1e-8f);
  float ang  = atan2f(lpy, lpx);
  float vang = atan2f(lvy, lvx);
  float* g = geom + idx*16;
  g[0]=px; g[1]=py; g[2]=vx; g[3]=vy; g[4]=th; g[5]=c; g[6]=s;
  g[7]=lpx; g[8]=lpy; g[9]=lvx; g[10]=lvy; g[11]=lfx; g[12]=lfy;
  float* r = relf + idx*16;
  r[0]=lpx; r[1]=lpy; r[2]=lvx; r[3]=lvy; r[4]=np_; r[5]=ang; r[6]=nv_; r[7]=vang; r[8]=th;
  r[9]=lpx; r[10]=lpy; r[11]=lvx; r[12]=lvy; r[13]=lfx; r[14]=lfy;
}

// ---------------------------------------------------------------------------
// Kcvt: bf16 copies for MFMA (w2b, pw2b, pw1b) + transposed packed-bf16
// weights wpk: [pr,pi,pn,hr,hi,hh,ow1,ow2,w1a,w1b], each [128][256] uint,
// wpk[m][k2][h] = bf16(M[h][2k2]) | bf16(M[h][2k2+1])<<16  (coalesced in h).
// ---------------------------------------------------------------------------
__global__ void k_cvt(const float* __restrict__ w2, const float* __restrict__ pw2,
                      const float* __restrict__ pw1,
                      const float* __restrict__ pr_w, const float* __restrict__ pi_w,
                      const float* __restrict__ pn_w, const float* __restrict__ hr_w,
                      const float* __restrict__ hi_w, const float* __restrict__ hh_w,
                      const float* __restrict__ ow1, const float* __restrict__ ow2,
                      const float* __restrict__ w1,
                      ushort_t* __restrict__ w2b, ushort_t* __restrict__ pw2b,
                      ushort_t* __restrict__ pw1b, uint_t* __restrict__ wpk) {
  int idx = blockIdx.x * 256 + threadIdx.x;
  if (idx < HH*HH) { w2b[idx] = f2b(w2[HH*HH + idx]); return; }
  idx -= HH*HH;
  if (idx < HH*HH) { pw2b[idx] = f2b(pw2[HH*HH + idx]); return; }
  idx -= HH*HH;
  if (idx < HH*32) {
    int col = idx >> 5, kk = idx & 31;
    pw1b[idx] = (kk < 24) ? f2b(pw1[col*24 + kk]) : (ushort_t)0;
    return;
  }
  idx -= HH*32;
  if (idx >= 10*32768) return;
  int m = idx >> 15, r = idx & 32767;
  int k2 = r >> 8, h = r & 255;
  const float* src; int o0;
  if      (m == 0) { src = pr_w; o0 = h*HH + 2*k2; }
  else if (m == 1) { src = pi_w; o0 = h*HH + 2*k2; }
  else if (m == 2) { src = pn_w; o0 = h*HH + 2*k2; }
  else if (m == 3) { src = hr_w; o0 = h*HH + 2*k2; }
  else if (m == 4) { src = hi_w; o0 = h*HH + 2*k2; }
  else if (m == 5) { src = hh_w; o0 = h*HH + 2*k2; }
  else if (m == 6) { src = ow1;  o0 = h*HH + 2*k2; }
  else if (m == 7) { src = ow2;  o0 = h*HH + 2*k2; }
  else if (m == 8) { src = w1 + HH*2*HH; o0 = h*(2*HH) + 2*k2; }        // w1a
  else             { src = w1 + HH*2*HH; o0 = h*(2*HH) + HH + 2*k2; }   // w1b
  uint_t lo = f2b(src[o0]);
  uint_t hi = f2b(src[o0 + 1]);
  wpk[idx] = lo | (hi << 16);
}

// ---------------------------------------------------------------------------
// K2: Ha = hidden@W1a.T + b1, Hb = hidden@W1b.T — coalesced packed weights.
// grid 512: block = (node n, batch-quarter), 4 rows each.
// ---------------------------------------------------------------------------
__global__ __launch_bounds__(256) void k_hab(const float* __restrict__ hidden,
                                             const uint_t* __restrict__ wpk,
                                             const float* __restrict__ b1,
                                             float* __restrict__ Ha,
                                             float* __restrict__ Hb) {
  int n = blockIdx.x >> 2, qtr = blockIdx.x & 3;
  int tid = threadIdx.x;
  __shared__ float x[4][HH];
  for (int q = 0; q < 4; ++q) {
    int b = qtr*4 + q;
    x[q][tid] = hidden[(b*NN + n)*HH + tid];
  }
  __syncthreads();
  const uint_t* pA = wpk + 8*32768;
  const uint_t* pB = wpk + 9*32768;
  float accA[4], accB[4];
  float bias = b1[HH + tid];
  #pragma unroll
  for (int q = 0; q < 4; ++q) { accA[q] = bias; accB[q] = 0.f; }
  for (int k2 = 0; k2 < 128; ++k2) {
    uint_t ua = pA[(k2<<8) + tid];
    uint_t ub = pB[(k2<<8) + tid];
    float wa0 = blo(ua), wa1 = bhi(ua);
    float wb0 = blo(ub), wb1 = bhi(ub);
    int k = k2 << 1;
    #pragma unroll
    for (int q = 0; q < 4; ++q) {
      float2 x2 = *(const float2*)(&x[q][k]);
      accA[q] += x2.x*wa0 + x2.y*wa1;
      accB[q] += x2.x*wb0 + x2.y*wb1;
    }
  }
  for (int q = 0; q < 4; ++q) {
    int b = qtr*4 + q;
    Ha[(b*NN + n)*HH + tid] = accA[q];
    Hb[(b*NN + n)*HH + tid] = accB[q];
  }
}

// ---------------------------------------------------------------------------
// K3: per (b, recv j, half): 64 senders per block. (unchanged from r4 cand.)
// ---------------------------------------------------------------------------
__global__ __launch_bounds__(256, 4) void k_edge(
    const float* __restrict__ Ha, const float* __restrict__ Hb,
    const float* __restrict__ geom, const float* __restrict__ edges,
    const ushort_t* __restrict__ w2b, const float* __restrict__ b2,
    const ushort_t* __restrict__ pw2b, const float* __restrict__ pb2,
    const ushort_t* __restrict__ pw1b, const float* __restrict__ pb1,
    float* __restrict__ agg0, float* __restrict__ agg1,
    float* __restrict__ pagg0, float* __restrict__ pagg1) {
  int half = blockIdx.x & 1;
  int j = (blockIdx.x >> 1) & 127;
  int b = blockIdx.x >> 8;
  int tid = threadIdx.x;
  int lane = tid & 63;
  int wv = tid >> 6;
  int lrow = lane & 15, lk = lane >> 4;

  __shared__ __align__(16) unsigned char m1s[64*512];   // 32 KB bf16 [64][256]
  __shared__ __align__(16) unsigned char attrB[64*64];  // 4 KB bf16 [64][32]
  __shared__ float HajS[HH];
  __shared__ float wgtS[64];
  __shared__ float gjS[13];

  HajS[tid] = Ha[(b*NN + j)*HH + tid];
  if (tid < 13) gjS[tid] = geom[(b*NN + j)*16 + tid];
  __syncthreads();

  if (tid < 64) {
    int il = tid;
    int i = half*64 + il;
    const float* gi = geom + (b*NN + i)*16;
    float dpx = gi[0]-gjS[0], dpy = gi[1]-gjS[1];
    float dvx = gi[2]-gjS[2], dvy = gi[3]-gjS[3];
    float dth = gi[4]-gjS[4];
    float cj = gjS[5], sj = gjS[6];
    float ci = gi[5],  si = gi[6];
    float ndp = sqrtf(dpx*dpx + dpy*dpy + 1e-8f);
    float ndv = sqrtf(dvx*dvx + dvy*dvy + 1e-8f);
    float r1x =  cj*dpx + sj*dpy, r1y = -sj*dpx + cj*dpy;
    float v1x =  cj*dvx + sj*dvy, v1y = -sj*dvx + cj*dvy;
    float r2x = -(ci*dpx + si*dpy), r2y = si*dpx - ci*dpy;
    float v2x = -(ci*dvx + si*dvy), v2y = si*dvx - ci*dvy;
    float f[24];
    f[0]=r1x; f[1]=r1y; f[2]=v1x; f[3]=v1y;
    f[4]=ndp; f[5]=atan2f(r1y, r1x);
    f[6]=ndv; f[7]=atan2f(v1y, v1x); f[8]=dth;
    f[9]=r2x; f[10]=r2y; f[11]=v2x; f[12]=v2y;
    f[13]=ndp; f[14]=atan2f(r2y, r2x);
    f[15]=ndv; f[16]=atan2f(v2y, v2x); f[17]=-dth;
    f[18]=gjS[7]; f[19]=gjS[8]; f[20]=gjS[9];
    f[21]=gjS[10]; f[22]=gjS[11]; f[23]=gjS[12];
    #pragma unroll
    for (int kb = 0; kb < 4; ++kb) {
      bf16x8 v;
      #pragma unroll
      for (int e = 0; e < 8; ++e) {
        int k = kb*8 + e;
        v[e] = (k < 24) ? (short)f2b(f[k]) : (short)0;
      }
      *reinterpret_cast<bf16x8*>(attrB + il*64 + ((kb*16) ^ ((il&3)<<4))) = v;
    }
    float w = 0.f;
    if (i != j) {
      int e = i*127 + (j < i ? j : j-1);
      w = edges[(b*EE + e)*2 + 1];
    }
    wgtS[il] = w;
  }

  {
    float haj = HajS[tid];
    const float* hb = Hb + (b*NN + half*64)*HH + tid;
    #pragma unroll
    for (int i0 = 0; i0 < 64; i0 += 8) {
      float v[8];
      #pragma unroll
      for (int u = 0; u < 8; ++u) v[u] = hb[(i0+u)*HH];
      #pragma unroll
      for (int u = 0; u < 8; ++u) {
        int row = i0 + u;
        *(ushort_t*)(m1s + row*512 + ((tid*2) ^ ((row&15)<<4))) =
            f2b(fast_tanh(haj + v[u]));
      }
    }
  }
  __syncthreads();

  f32x4 zero = {0.f, 0.f, 0.f, 0.f};

  // GEMM1
  {
    f32x4 acc[4][4];
    #pragma unroll
    for (int rt = 0; rt < 4; ++rt)
      #pragma unroll
      for (int nt = 0; nt < 4; ++nt) acc[rt][nt] = zero;
    for (int kk = 0; kk < 8; ++kk) {
      bf16x8 afr[4];
      #pragma unroll
      for (int rt = 0; rt < 4; ++rt) {
        int row = rt*16 + lrow;
        afr[rt] = *reinterpret_cast<const bf16x8*>(
            m1s + row*512 + ((kk*64 + lk*16) ^ ((row&15)<<4)));
      }
      #pragma unroll
      for (int nt = 0; nt < 4; ++nt) {
        int col = wv*64 + nt*16 + lrow;
        bf16x8 bfr = *reinterpret_cast<const bf16x8*>(w2b + col*HH + kk*32 + lk*8);
        #pragma unroll
        for (int rt = 0; rt < 4; ++rt)
          acc[rt][nt] = __builtin_amdgcn_mfma_f32_16x16x32_bf16(afr[rt], bfr, acc[rt][nt], 0, 0, 0);
      }
    }
    float* aggOut = half ? agg1 : agg0;
    #pragma unroll
    for (int nt = 0; nt < 4; ++nt) {
      int col = wv*64 + nt*16 + lrow;
      float bias = b2[col];
      float p = 0.f;
      #pragma unroll
      for (int rt = 0; rt < 4; ++rt)
        #pragma unroll
        for (int r = 0; r < 4; ++r) {
          int row = rt*16 + lk*4 + r;
          p += fast_tanh(acc[rt][nt][r] + bias) * wgtS[row];
        }
      p += __shfl_xor(p, 16);
      p += __shfl_xor(p, 32);
      if (lane < 16)
        aggOut[(b*NN + j)*HH + wv*64 + nt*16 + lane] = p * (1.0f/127.0f);
    }
  }
  __syncthreads();

  // B2 via MFMA
  {
    f32x4 acc[4][4];
    #pragma unroll
    for (int rt = 0; rt < 4; ++rt)
      #pragma unroll
      for (int nt = 0; nt < 4; ++nt) acc[rt][nt] = zero;
    bf16x8 afr[4];
    #pragma unroll
    for (int rt = 0; rt < 4; ++rt) {
      int row = rt*16 + lrow;
      afr[rt] = *reinterpret_cast<const bf16x8*>(
          attrB + row*64 + ((lk*16) ^ ((lrow&3)<<4)));
    }
    #pragma unroll
    for (int nt = 0; nt < 4; ++nt) {
      int col = wv*64 + nt*16 + lrow;
      bf16x8 bfr = *reinterpret_cast<const bf16x8*>(pw1b + col*32 + lk*8);
      #pragma unroll
      for (int rt = 0; rt < 4; ++rt)
        acc[rt][nt] = __builtin_amdgcn_mfma_f32_16x16x32_bf16(afr[rt], bfr, acc[rt][nt], 0, 0, 0);
    }
    #pragma unroll
    for (int nt = 0; nt < 4; ++nt) {
      int col = wv*64 + nt*16 + lrow;
      float bias = pb1[col];
      #pragma unroll
      for (int rt = 0; rt < 4; ++rt)
        #pragma unroll
        for (int r = 0; r < 4; ++r) {
          int row = rt*16 + lk*4 + r;
          *(ushort_t*)(m1s + row*512 + ((col*2) ^ ((row&15)<<4))) =
              f2b(fmaxf(acc[rt][nt][r] + bias, 0.f));
        }
    }
  }
  __syncthreads();

  // GEMM2
  {
    f32x4 acc[4][4];
    #pragma unroll
    for (int rt = 0; rt < 4; ++rt)
      #pragma unroll
      for (int nt = 0; nt < 4; ++nt) acc[rt][nt] = zero;
    for (int kk = 0; kk < 8; ++kk) {
      bf16x8 afr[4];
      #pragma unroll
      for (int rt = 0; rt < 4; ++rt) {
        int row = rt*16 + lrow;
        afr[rt] = *reinterpret_cast<const bf16x8*>(
            m1s + row*512 + ((kk*64 + lk*16) ^ ((row&15)<<4)));
      }
      #pragma unroll
      for (int nt = 0; nt < 4; ++nt) {
        int col = wv*64 + nt*16 + lrow;
        bf16x8 bfr = *reinterpret_cast<const bf16x8*>(pw2b + col*HH + kk*32 + lk*8);
        #pragma unroll
        for (int rt = 0; rt < 4; ++rt)
          acc[rt][nt] = __builtin_amdgcn_mfma_f32_16x16x32_bf16(afr[rt], bfr, acc[rt][nt], 0, 0, 0);
      }
    }
    float* paggOut = half ? pagg1 : pagg0;
    #pragma unroll
    for (int nt = 0; nt < 4; ++nt) {
      int col = wv*64 + nt*16 + lrow;
      float bias = pb2[col];
      float p = 0.f;
      #pragma unroll
      for (int rt = 0; rt < 4; ++rt)
        #pragma unroll
        for (int r = 0; r < 4; ++r) {
          int row = rt*16 + lk*4 + r;
          p += fmaxf(acc[rt][nt][r] + bias, 0.f) * wgtS[row];
        }
      p += __shfl_xor(p, 16);
      p += __shfl_xor(p, 32);
      if (lane < 16)
        paggOut[(b*NN + j)*HH + wv*64 + nt*16 + lane] = p * (1.0f/127.0f);
    }
  }
}

// ---------------------------------------------------------------------------
// K4: GRU gates + output MLP — coalesced packed transposed weights.
// grid 512: block = (node n, batch-quarter), 4 rows.
// ---------------------------------------------------------------------------
__global__ __launch_bounds__(256) void k_gru(
    const float* __restrict__ inputs, const float* __restrict__ hidden,
    const float* __restrict__ geom, const float* __restrict__ relf,
    const float* __restrict__ agg0, const float* __restrict__ agg1,
    const float* __restrict__ pagg0, const float* __restrict__ pagg1,
    const uint_t* __restrict__ wpk,
    const float* __restrict__ pr_b, const float* __restrict__ pi_b,
    const float* __restrict__ pn_b,
    const float* __restrict__ ir_w, const float* __restrict__ ir_b,
    const float* __restrict__ ii_w, const float* __restrict__ ii_b,
    const float* __restrict__ in_w, const float* __restrict__ in_b,
    const float* __restrict__ ob1, const float* __restrict__ ob2,
    const float* __restrict__ ow3, const float* __restrict__ ob3,
    float* __restrict__ out_o, float* __restrict__ out_h) {
  int n = blockIdx.x >> 2, qtr = blockIdx.x & 3;
  int tid = threadIdx.x;
  __shared__ float paS[4][HH], agS[4][HH], hS[4][HH], t0S[4][HH], t1S[4][HH];
  __shared__ float relS[4][16];
  __shared__ float predS[4][4];

  for (int q = 0; q < 4; ++q) {
    int b = qtr*4 + q;
    int base = (b*NN + n)*HH;
    paS[q][tid] = pagg0[base + tid] + pagg1[base + tid];
    agS[q][tid] = agg0[base + tid] + agg1[base + tid];
    hS[q][tid]  = hidden[base + tid];
  }
  if (tid < 64) {
    int q = tid >> 4, k = tid & 15;
    int b = qtr*4 + q;
    relS[q][k] = (k < 15) ? relf[(b*NN + n)*16 + k] : 0.f;
  }
  __syncthreads();

  int h = tid;
  const uint_t* pPr = wpk;
  const uint_t* pPi = wpk + 32768;
  const uint_t* pPn = wpk + 2*32768;
  const uint_t* pHr = wpk + 3*32768;
  const uint_t* pHi = wpk + 4*32768;
  const uint_t* pHh = wpk + 5*32768;
  const uint_t* pO1 = wpk + 6*32768;
  const uint_t* pO2 = wpk + 7*32768;

  float aR[4], aI[4], aN[4], aH[4];
  float br = ir_b[h] + pr_b[h];
  float bi = ii_b[h] + pi_b[h];
  float bn = in_b[h] + pn_b[h];
  #pragma unroll
  for (int q = 0; q < 4; ++q) { aR[q]=br; aI[q]=bi; aN[q]=bn; aH[q]=0.f; }

  for (int k = 0; k < 15; ++k) {
    float wr = ir_w[h*15+k], wi = ii_w[h*15+k], wn = in_w[h*15+k];
    #pragma unroll
    for (int q = 0; q < 4; ++q) {
      float x = relS[q][k];
      aR[q] += x*wr; aI[q] += x*wi; aN[q] += x*wn;
    }
  }

  for (int k2 = 0; k2 < 128; ++k2) {
    uint_t upr = pPr[(k2<<8) + h];
    uint_t upi = pPi[(k2<<8) + h];
    uint_t upn = pPn[(k2<<8) + h];
    uint_t uhr = pHr[(k2<<8) + h];
    uint_t uhi = pHi[(k2<<8) + h];
    uint_t uhh = pHh[(k2<<8) + h];
    float pr0 = blo(upr), pr1 = bhi(upr);
    float pi0 = blo(upi), pi1 = bhi(upi);
    float pn0 = blo(upn), pn1 = bhi(upn);
    float hr0 = blo(uhr), hr1 = bhi(uhr);
    float hi0 = blo(uhi), hi1 = bhi(uhi);
    float hh0 = blo(uhh), hh1 = bhi(uhh);
    int k = k2 << 1;
    #pragma unroll
    for (int q = 0; q < 4; ++q) {
      float2 xp = *(const float2*)(&paS[q][k]);
      float2 xa = *(const float2*)(&agS[q][k]);
      aR[q] += xp.x*pr0 + xp.y*pr1 + xa.x*hr0 + xa.y*hr1;
      aI[q] += xp.x*pi0 + xp.y*pi1 + xa.x*hi0 + xa.y*hi1;
      aN[q] += xp.x*pn0 + xp.y*pn1;
      aH[q] += xa.x*hh0 + xa.y*hh1;
    }
  }

  #pragma unroll
  for (int q = 0; q < 4; ++q) {
    int b = qtr*4 + q;
    float r  = fast_sigmoid(aR[q]);
    float ig = fast_sigmoid(aI[q]);
    float ng = fast_tanh(aN[q] + r*aH[q]);
    float hn = (1.f - ig)*ng + ig*hS[q][h];
    out_h[(b*NN + n)*HH + h] = hn;
    t0S[q][h] = hn;
  }
  __syncthreads();

  { // h1 = relu(hn @ ow1.T + ob1)
    float a1[4];
    float bias = ob1[h];
    #pragma unroll
    for (int q = 0; q < 4; ++q) a1[q] = bias;
    for (int k2 = 0; k2 < 128; ++k2) {
      uint_t u = pO1[(k2<<8) + h];
      float w0 = blo(u), w1 = bhi(u);
      int k = k2 << 1;
      #pragma unroll
      for (int q = 0; q < 4; ++q) {
        float2 x2 = *(const float2*)(&t0S[q][k]);
        a1[q] += x2.x*w0 + x2.y*w1;
      }
    }
    __syncthreads();
    #pragma unroll
    for (int q = 0; q < 4; ++q) t1S[q][h] = fmaxf(a1[q], 0.f);
  }
  __syncthreads();

  { // h2 = relu(h1 @ ow2.T + ob2) -> t0S
    float a2[4];
    float bias = ob2[h];
    #pragma unroll
    for (int q = 0; q < 4; ++q) a2[q] = bias;
    for (int k2 = 0; k2 < 128; ++k2) {
      uint_t u = pO2[(k2<<8) + h];
      float w0 = blo(u), w1 = bhi(u);
      int k = k2 << 1;
      #pragma unroll
      for (int q = 0; q < 4; ++q) {
        float2 x2 = *(const float2*)(&t1S[q][k]);
        a2[q] += x2.x*w0 + x2.y*w1;
      }
    }
    __syncthreads();
    #pragma unroll
    for (int q = 0; q < 4; ++q) t0S[q][h] = fmaxf(a2[q], 0.f);
  }
  __syncthreads();

  if (tid < 16) {
    int o = tid >> 2, q = tid & 3;
    float acc = ob3[o];
    for (int k = 0; k < HH; ++k) acc += t0S[q][k]*ow3[o*HH + k];
    predS[q][o] = acc;
  }
  __syncthreads();
  if (tid < 4) {
    int q = tid;
    int b = qtr*4 + q;
    const float* g = geom + (b*NN + n)*16;
    float c = g[5], s = g[6];
    float p0 = predS[q][0], p1 = predS[q][1], p2 = predS[q][2], p3 = predS[q][3];
    int base = (b*NN + n)*4;
    out_o[base+0] = inputs[base+0] + (c*p0 - s*p1);
    out_o[base+1] = inputs[base+1] + (s*p0 + c*p1);
    out_o[base+2] = inputs[base+2] + (c*p2 - s*p3);
    out_o[base+3] = inputs[base+3] + (s*p2 + c*p3);
  }
}

// ---------------------------------------------------------------------------
extern "C" void kernel_launch(void* const* d_in, const int* in_sizes, int n_in,
                              void* d_out, int out_size, void* d_ws, size_t ws_size,
                              hipStream_t stream) {
  const float* inputs    = (const float*)d_in[0];
  const float* hidden    = (const float*)d_in[1];
  const float* edges     = (const float*)d_in[2];
  const float* pfield    = (const float*)d_in[3];
  const float* msg_fc1_w = (const float*)d_in[4];
  const float* msg_fc1_b = (const float*)d_in[5];
  const float* msg_fc2_w = (const float*)d_in[6];
  const float* msg_fc2_b = (const float*)d_in[7];
  const float* pm_fc1_w  = (const float*)d_in[8];
  const float* pm_fc1_b  = (const float*)d_in[9];
  const float* pm_fc2_w  = (const float*)d_in[10];
  const float* pm_fc2_b  = (const float*)d_in[11];
  const float* hr_w = (const float*)d_in[12];
  const float* hi_w = (const float*)d_in[13];
  const float* hh_w = (const float*)d_in[14];
  const float* pr_w = (const float*)d_in[15];
  const float* pr_b = (const float*)d_in[16];
  const float* pi_w = (const float*)d_in[17];
  const float* pi_b = (const float*)d_in[18];
  const float* pn_w = (const float*)d_in[19];
  const float* pn_b = (const float*)d_in[20];
  const float* ir_w = (const float*)d_in[21];
  const float* ir_b = (const float*)d_in[22];
  const float* ii_w = (const float*)d_in[23];
  const float* ii_b = (const float*)d_in[24];
  const float* in_w = (const float*)d_in[25];
  const float* in_b = (const float*)d_in[26];
  const float* ow1  = (const float*)d_in[27];
  const float* ob1  = (const float*)d_in[28];
  const float* ow2  = (const float*)d_in[29];
  const float* ob2  = (const float*)d_in[30];
  const float* ow3  = (const float*)d_in[31];
  const float* ob3  = (const float*)d_in[32];

  float* ws   = (float*)d_ws;
  float* geom = ws;                 // 32768 f32
  float* relf = geom + 32768;       // 32768
  float* Ha   = relf + 32768;       // 524288
  float* Hb   = Ha   + 524288;      // 524288
  float* agg0 = Hb   + 524288;      // 524288
  float* agg1 = agg0 + 524288;      // 524288
  float* pagg0= agg1 + 524288;      // 524288
  float* pagg1= pagg0+ 524288;      // 524288
  ushort_t* w2b  = (ushort_t*)(pagg1 + 524288);  // 65536 bf16
  ushort_t* pw2b = w2b + HH*HH;                  // 65536 bf16
  ushort_t* pw1b = pw2b + HH*HH;                 // 8192 bf16
  uint_t*   wpk  = (uint_t*)(pw1b + HH*32);      // 10*32768 uint (1.25 MB)

  float* out_o = (float*)d_out;           // (B,N,4)
  float* out_h = out_o + BB*NN*4;         // (B,N,H)

  k_node_geom<<<dim3(8), dim3(256), 0, stream>>>(inputs, pfield, geom, relf);
  // threads: 65536+65536+8192+327680 = 466944 -> 1824 blocks
  k_cvt<<<dim3(1824), dim3(256), 0, stream>>>(msg_fc2_w, pm_fc2_w,
      pm_fc1_w + HH*24, pr_w, pi_w, pn_w, hr_w, hi_w, hh_w, ow1, ow2,
      msg_fc1_w, w2b, pw2b, pw1b, wpk);
  k_hab<<<dim3(512), dim3(256), 0, stream>>>(hidden, wpk, msg_fc1_b, Ha, Hb);
  k_edge<<<dim3(BB*NN*2), dim3(256), 0, stream>>>(Ha, Hb, geom, edges,
      w2b, msg_fc2_b + HH, pw2b, pm_fc2_b + HH,
      pw1b, pm_fc1_b + HH, agg0, agg1, pagg0, pagg1);
  k_gru<<<dim3(512), dim3(256), 0, stream>>>(inputs, hidden, geom, relf,
      agg0, agg1, pagg0, pagg1, wpk,
      pr_b, pi_b, pn_b, ir_w, ir_b, ii_w, ii_b, in_w, in_b,
      ob1, ob2, ow3, ob3, out_o, out_h);
}